// Round 2
// baseline (269.320 us; speedup 1.0000x reference)
//
#include <hip/hip_runtime.h>
#include <hip/hip_bf16.h>

// Problem constants (from reference): N=100000, E=3200000, C=4, H=64
// All float inputs are float32; edge_index is int32 (harness converts int64).
// Output: concat(pm10_next[N], delta_pm10[N]) as float32.
#define HID 64
#define EPSV 1e-8f
#define BLK 256
#define RPT 4   // edges per thread

// Edge kernel: per edge build feat[10], run 64x10 MLP + relu, fold the linear
// head to a scalar s_e = sum_h head_w[h]*relu_h, atomicAdd into delta_acc[dst].
__global__ __launch_bounds__(BLK) void edge_kernel(
    const float4* __restrict__ x,       // N x 4 f32 rows (16B)
    const float2* __restrict__ pos,     // N x 2 f32 rows (8B)
    const float*  __restrict__ mlp_w,   // 64*10 f32, row-major [h][j]
    const float*  __restrict__ mlp_b,   // 64 f32
    const float*  __restrict__ head_w,  // 64 f32
    const int*    __restrict__ srcs,
    const int*    __restrict__ dsts,
    float* __restrict__ delta_acc,
    int E)
{
    // Weight rows in LDS as [w0..w9, bias, head_w] = 3 x float4 per h.
    // Reads in the h-loop are wave-uniform -> LDS broadcast, conflict-free.
    __shared__ float4 wrow[HID * 3];
    int tid = threadIdx.x;
    for (int h = tid; h < HID; h += BLK) {
        const float* wr = mlp_w + h * 10;
        float4 a, b, c;
        a.x = wr[0]; a.y = wr[1]; a.z = wr[2]; a.w = wr[3];
        b.x = wr[4]; b.y = wr[5]; b.z = wr[6]; b.w = wr[7];
        c.x = wr[8]; c.y = wr[9]; c.z = mlp_b[h]; c.w = head_w[h];
        wrow[h * 3 + 0] = a;
        wrow[h * 3 + 1] = b;
        wrow[h * 3 + 2] = c;
    }
    __syncthreads();

    long base = (long)blockIdx.x * (BLK * RPT) + tid;  // r-th edge at base+r*BLK (coalesced)

    float f[RPT][10];
    int   edst[RPT];
    bool  valid[RPT];

    #pragma unroll
    for (int r = 0; r < RPT; r++) {
        long e = base + (long)r * BLK;
        bool ok = (e < (long)E);
        valid[r] = ok;
        long ee = ok ? e : 0;
        int s = srcs[ee];
        int d = dsts[ee];
        edst[r] = d;
        float4 xs = x[s];
        float4 xd = x[d];
        float2 ps = pos[s];
        float2 pd = pos[d];
        float d0 = ps.x - pd.x;
        float d1 = ps.y - pd.y;
        float dist = sqrtf(fmaf(d0, d0, fmaf(d1, d1, EPSV)));
        float inv = 1.0f / dist;
        float wind = (xs.y * d0 + xs.z * d1) * inv;  // u10[src]*dhat0 + v10[src]*dhat1
        f[r][0] = xd.x;
        f[r][1] = xd.y;
        f[r][2] = xd.z;
        f[r][3] = xd.w;
        f[r][4] = xs.x;
        f[r][5] = xs.y;
        f[r][6] = xs.z;
        f[r][7] = xs.w;
        f[r][8] = wind;
        f[r][9] = dist;
    }

    float sacc[RPT];
    #pragma unroll
    for (int r = 0; r < RPT; r++) sacc[r] = 0.0f;

    for (int h = 0; h < HID; h++) {
        float4 w0 = wrow[h * 3 + 0];
        float4 w1 = wrow[h * 3 + 1];
        float4 w2 = wrow[h * 3 + 2];
        #pragma unroll
        for (int r = 0; r < RPT; r++) {
            float a = w2.z;
            a = fmaf(w0.x, f[r][0], a);
            a = fmaf(w0.y, f[r][1], a);
            a = fmaf(w0.z, f[r][2], a);
            a = fmaf(w0.w, f[r][3], a);
            a = fmaf(w1.x, f[r][4], a);
            a = fmaf(w1.y, f[r][5], a);
            a = fmaf(w1.z, f[r][6], a);
            a = fmaf(w1.w, f[r][7], a);
            a = fmaf(w2.x, f[r][8], a);
            a = fmaf(w2.y, f[r][9], a);
            a = fmaxf(a, 0.0f);
            sacc[r] = fmaf(w2.w, a, sacc[r]);
        }
    }

    #pragma unroll
    for (int r = 0; r < RPT; r++) {
        if (valid[r]) atomicAdd(&delta_acc[edst[r]], sacc[r]);
    }
}

// Node kernel: delta = acc + head_b; pm10_next = softplus(x0 + delta).
__global__ __launch_bounds__(BLK) void node_kernel(
    const float4* __restrict__ x,
    const float*  __restrict__ delta_acc,
    const float*  __restrict__ head_b,
    float* __restrict__ out,
    int N)
{
    int n = blockIdx.x * BLK + threadIdx.x;
    if (n >= N) return;
    float delta = delta_acc[n] + head_b[0];
    float v = x[n].x + delta;
    // stable softplus: max(v,0) + log1p(exp(-|v|))
    float sp = fmaxf(v, 0.0f) + log1pf(expf(-fabsf(v)));
    out[n] = sp;
    out[N + n] = delta;
}

extern "C" void kernel_launch(void* const* d_in, const int* in_sizes, int n_in,
                              void* d_out, int out_size, void* d_ws, size_t ws_size,
                              hipStream_t stream) {
    const float4* x      = (const float4*)d_in[0];
    const float2* pos    = (const float2*)d_in[1];
    const float*  mlp_w  = (const float*)d_in[2];
    const float*  mlp_b  = (const float*)d_in[3];
    const float*  head_w = (const float*)d_in[4];
    const float*  head_b = (const float*)d_in[5];
    const int*    ei     = (const int*)d_in[6];

    int N = in_sizes[0] / 4;   // 100000
    int E = in_sizes[6] / 2;   // 3200000
    const int* srcs = ei;
    const int* dsts = ei + E;

    float* delta_acc = (float*)d_ws;
    hipMemsetAsync(delta_acc, 0, (size_t)N * sizeof(float), stream);

    int edge_blocks = (E + BLK * RPT - 1) / (BLK * RPT);
    edge_kernel<<<edge_blocks, BLK, 0, stream>>>(x, pos, mlp_w, mlp_b, head_w,
                                                 srcs, dsts, delta_acc, E);

    int node_blocks = (N + BLK - 1) / BLK;
    node_kernel<<<node_blocks, BLK, 0, stream>>>(x, delta_acc, head_b,
                                                 (float*)d_out, N);
}